// Round 7
// baseline (1224.426 us; speedup 1.0000x reference)
//
#include <hip/hip_runtime.h>

constexpr int N  = 100000;
constexpr int E  = 1600000;
constexpr int IN = 128, HID = 64, OUTC = 32;

// coarse radix partition params
constexpr int SHIFT = 7;                       // 128 nodes per bucket
constexpr int NPB   = 1 << SHIFT;              // 128
constexpr int NB    = (N + NPB - 1) / NPB;     // 782 buckets
constexpr int PB    = 128;                     // partition blocks
constexpr int CHUNK = E / PB;                  // 12500 (exact)

// ---- bf16 helpers (manual, RNE) ----
__device__ __forceinline__ unsigned short f2bf(float f) {
    union { float f; unsigned int u; } v; v.f = f;
    unsigned int u = v.u;
    unsigned int r = (u + 0x7fffu + ((u >> 16) & 1u)) >> 16;
    return (unsigned short)r;
}
__device__ __forceinline__ float bf2f(unsigned short h) {
    union { unsigned int u; float f; } v; v.u = ((unsigned int)h) << 16;
    return v.f;
}

// ---------------- coarse histogram: gcnt[b] = #edges with dst>>7 == b ----------------
__global__ __launch_bounds__(256) void k_hist(const int* __restrict__ dst,
                                              int* __restrict__ gcnt) {
    __shared__ int h[NB];
    for (int i = threadIdx.x; i < NB; i += 256) h[i] = 0;
    __syncthreads();
    const int tid = blockIdx.x * 256 + threadIdx.x, nt = gridDim.x * 256;
    for (int e = tid; e < E; e += nt) atomicAdd(&h[dst[e] >> SHIFT], 1);
    __syncthreads();
    for (int i = threadIdx.x; i < NB; i += 256)
        if (h[i]) atomicAdd(&gcnt[i], h[i]);
}

// ---------------- scan bucket totals (padded to 8 entries = 32B alignment) ----------------
__global__ __launch_bounds__(1024) void k_bscan(const int* __restrict__ gcnt,
                                                int* __restrict__ bbase,
                                                int* __restrict__ cursor) {
    __shared__ int sb[1024];
    const int t = threadIdx.x;
    int v = (t < NB) ? ((gcnt[t] + 7) & ~7) : 0;   // pad: aligned uint4 reads in agg
    sb[t] = v; __syncthreads();
    for (int off = 1; off < 1024; off <<= 1) {
        int x = (t >= off) ? sb[t - off] : 0;
        __syncthreads();
        sb[t] += x;
        __syncthreads();
    }
    if (t < NB) { int ex = sb[t] - v; bbase[t] = ex; cursor[t] = ex; }
}

// ---------------- partition edges into buckets (packed (dstLow<<17)|src) ----------------
__global__ __launch_bounds__(256) void k_part(const int* __restrict__ src,
                                              const int* __restrict__ dst,
                                              int* __restrict__ cursor,
                                              unsigned* __restrict__ packed) {
    __shared__ int lh[NB], lb[NB], lc[NB];
    const int t = threadIdx.x;
    const int beg = blockIdx.x * CHUNK, end = beg + CHUNK;
    for (int i = t; i < NB; i += 256) lh[i] = 0;
    __syncthreads();
    for (int e = beg + t; e < end; e += 256) atomicAdd(&lh[dst[e] >> SHIFT], 1);
    __syncthreads();
    for (int i = t; i < NB; i += 256) {
        lb[i] = lh[i] ? atomicAdd(&cursor[i], lh[i]) : 0;
        lc[i] = 0;
    }
    __syncthreads();
    for (int e = beg + t; e < end; e += 256) {
        int d = dst[e], b = d >> SHIFT;
        int idx = atomicAdd(&lc[b], 1);
        packed[lb[b] + idx] = ((unsigned)(d & (NPB - 1)) << 17) | (unsigned)src[e];
    }
}

// ---------------- per-bucket degree -> dinv ----------------
__global__ __launch_bounds__(256) void k_dinvb(const int* __restrict__ bbase,
                                               const int* __restrict__ gcnt,
                                               const unsigned* __restrict__ packed,
                                               float* __restrict__ dinv) {
    __shared__ int cnt[NPB];
    const int t = threadIdx.x, bk = blockIdx.x;
    const int base = bbase[bk], cntE = gcnt[bk];
    if (t < NPB) cnt[t] = 0;
    __syncthreads();
    for (int i = t; i < cntE; i += 256) atomicAdd(&cnt[packed[base + i] >> 17], 1);
    __syncthreads();
    const int node = (bk << SHIFT) + t;
    if (t < NPB && node < N) dinv[node] = rsqrtf((float)cnt[t] + 1.0f);  // +1 self loop
}

// ---------------- GEMM1: Hs = bf16(dinv[row] * (X @ W1)) ----------------
__global__ __launch_bounds__(256) void k_gemm1(const float* __restrict__ X,
                                               const float* __restrict__ W,
                                               const float* __restrict__ dinv,
                                               unsigned short* __restrict__ Hs) {
    constexpr int R  = 32;
    constexpr int XS = IN + 4;
    __shared__ float ws[IN * HID];             // 32 KB
    __shared__ float xs[R * XS];
    const int t    = threadIdx.x;
    const int row0 = blockIdx.x * R;

    for (int i = t; i < IN * HID / 4; i += 256)
        ((float4*)ws)[i] = ((const float4*)W)[i];
    for (int i = t; i < R * IN / 4; i += 256) {
        int r = i / (IN / 4), k4 = i % (IN / 4);
        *(float4*)&xs[r * XS + k4 * 4] =
            ((const float4*)(X + (size_t)(row0 + r) * IN))[k4];
    }
    __syncthreads();

    const int col0 = (t & 15) * 4;
    const int r0   = (t >> 4) * 2;
    float4 a0 = {0, 0, 0, 0}, a1 = {0, 0, 0, 0};
    for (int k = 0; k < IN; ++k) {
        float4 w = *(const float4*)&ws[k * HID + col0];
        float x0 = xs[r0 * XS + k];
        float x1 = xs[(r0 + 1) * XS + k];
        a0.x += x0 * w.x; a0.y += x0 * w.y; a0.z += x0 * w.z; a0.w += x0 * w.w;
        a1.x += x1 * w.x; a1.y += x1 * w.y; a1.z += x1 * w.z; a1.w += x1 * w.w;
    }
    const float d0 = dinv[row0 + r0];
    const float d1 = dinv[row0 + r0 + 1];
    ushort4 p0 = {f2bf(a0.x * d0), f2bf(a0.y * d0), f2bf(a0.z * d0), f2bf(a0.w * d0)};
    ushort4 p1 = {f2bf(a1.x * d1), f2bf(a1.y * d1), f2bf(a1.z * d1), f2bf(a1.w * d1)};
    *(ushort4*)(Hs + (size_t)(row0 + r0) * HID + col0)       = p0;
    *(ushort4*)(Hs + (size_t)(row0 + r0 + 1) * HID + col0)   = p1;
}

// ---------------- agg1: LDS-accumulated aggregation, layer 1 ----------------
// Block = one 128-node bucket. acc[128][64] fp32 in LDS. Wave reads 4 packed
// entries (uniform -> scalar), issues 4 independent row gathers, ds_adds them
// (64 lanes / 32 banks = 2-way = free). Epilogue fuses self-loop+bias+relu.
__global__ __launch_bounds__(512) void k_agg1(const int* __restrict__ bbase,
                                              const int* __restrict__ gcnt,
                                              const unsigned* __restrict__ packed,
                                              const float* __restrict__ dinv,
                                              const unsigned short* __restrict__ Hs,
                                              const float* __restrict__ bias,
                                              float* __restrict__ O1) {
    __shared__ float acc[NPB * HID];           // 32 KB
    const int t = threadIdx.x, bk = blockIdx.x;
    for (int i = t; i < NPB * HID / 4; i += 512)
        ((float4*)acc)[i] = float4{0, 0, 0, 0};
    __syncthreads();

    const int base = bbase[bk], cntE = gcnt[bk];
    const int wave = t >> 6, c = t & 63;
    const int full = cntE & ~3;
    for (int i = wave * 4; i < full; i += 32) {
        uint4 p4 = *(const uint4*)&packed[base + i];   // base%8==0 -> 16B aligned
        float h0 = bf2f(Hs[(size_t)(p4.x & 0x1FFFFu) * HID + c]);
        float h1 = bf2f(Hs[(size_t)(p4.y & 0x1FFFFu) * HID + c]);
        float h2 = bf2f(Hs[(size_t)(p4.z & 0x1FFFFu) * HID + c]);
        float h3 = bf2f(Hs[(size_t)(p4.w & 0x1FFFFu) * HID + c]);
        atomicAdd(&acc[(p4.x >> 17) * HID + c], h0);
        atomicAdd(&acc[(p4.y >> 17) * HID + c], h1);
        atomicAdd(&acc[(p4.z >> 17) * HID + c], h2);
        atomicAdd(&acc[(p4.w >> 17) * HID + c], h3);
    }
    if (wave == 0) {
        for (int i = full; i < cntE; ++i) {
            unsigned p = packed[base + i];
            float h = bf2f(Hs[(size_t)(p & 0x1FFFFu) * HID + c]);
            atomicAdd(&acc[(p >> 17) * HID + c], h);
        }
    }
    __syncthreads();

    const int node0 = bk << SHIFT;
    for (int k = 0; k < NPB * HID / 512; ++k) {
        int idx = t + k * 512;
        int node = node0 + (idx >> 6), ch = idx & 63;
        if (node < N) {
            float o = acc[idx] + bf2f(Hs[(size_t)node * HID + ch]);  // self loop (pre-scaled)
            O1[(size_t)node * HID + ch] = fmaxf(o * dinv[node] + bias[ch], 0.0f);
        }
    }
}

// ---------------- GEMM2: H2s = bf16(dinv[row] * (O1 @ W2)), O1 pre-relu'd ----------------
__global__ __launch_bounds__(256) void k_gemm2(const float* __restrict__ O1,
                                               const float* __restrict__ W,
                                               const float* __restrict__ dinv,
                                               unsigned short* __restrict__ H2s) {
    constexpr int R  = 32;
    constexpr int XS = HID + 4;
    __shared__ float ws[HID * OUTC];
    __shared__ float xs[R * XS];
    const int t    = threadIdx.x;
    const int row0 = blockIdx.x * R;

    for (int i = t; i < HID * OUTC / 4; i += 256)
        ((float4*)ws)[i] = ((const float4*)W)[i];
    for (int i = t; i < R * HID / 4; i += 256) {
        int r = i / (HID / 4), k4 = i % (HID / 4);
        *(float4*)&xs[r * XS + k4 * 4] =
            ((const float4*)(O1 + (size_t)(row0 + r) * HID))[k4];
    }
    __syncthreads();

    const int col0 = (t & 7) * 4;
    const int r    = t >> 3;
    float4 a = {0, 0, 0, 0};
    for (int k = 0; k < HID; ++k) {
        float4 w = *(const float4*)&ws[k * OUTC + col0];
        float x  = xs[r * XS + k];
        a.x += x * w.x; a.y += x * w.y; a.z += x * w.z; a.w += x * w.w;
    }
    const float dd = dinv[row0 + r];
    ushort4 p = {f2bf(a.x * dd), f2bf(a.y * dd), f2bf(a.z * dd), f2bf(a.w * dd)};
    *(ushort4*)(H2s + (size_t)(row0 + r) * OUTC + col0) = p;
}

// ---------------- agg2: LDS-accumulated aggregation, layer 2 (32 ch) ----------------
// Half-wave per edge: wave reads 8 packed entries, halves process 4 each.
__global__ __launch_bounds__(512) void k_agg2(const int* __restrict__ bbase,
                                              const int* __restrict__ gcnt,
                                              const unsigned* __restrict__ packed,
                                              const float* __restrict__ dinv,
                                              const unsigned short* __restrict__ H2s,
                                              const float* __restrict__ bias,
                                              float* __restrict__ out) {
    __shared__ float acc[NPB * OUTC];          // 16 KB
    const int t = threadIdx.x, bk = blockIdx.x;
    for (int i = t; i < NPB * OUTC / 4; i += 512)
        ((float4*)acc)[i] = float4{0, 0, 0, 0};
    __syncthreads();

    const int base = bbase[bk], cntE = gcnt[bk];
    const int wave = t >> 6, lane = t & 63;
    const int c = lane & 31, half = lane >> 5;
    const int full = cntE & ~7;
    for (int i = wave * 8; i < full; i += 64) {
        uint4 qa = *(const uint4*)&packed[base + i];
        uint4 qb = *(const uint4*)&packed[base + i + 4];
        unsigned p0 = half ? qb.x : qa.x;
        unsigned p1 = half ? qb.y : qa.y;
        unsigned p2 = half ? qb.z : qa.z;
        unsigned p3 = half ? qb.w : qa.w;
        float h0 = bf2f(H2s[(size_t)(p0 & 0x1FFFFu) * OUTC + c]);
        float h1 = bf2f(H2s[(size_t)(p1 & 0x1FFFFu) * OUTC + c]);
        float h2 = bf2f(H2s[(size_t)(p2 & 0x1FFFFu) * OUTC + c]);
        float h3 = bf2f(H2s[(size_t)(p3 & 0x1FFFFu) * OUTC + c]);
        atomicAdd(&acc[(p0 >> 17) * OUTC + c], h0);
        atomicAdd(&acc[(p1 >> 17) * OUTC + c], h1);
        atomicAdd(&acc[(p2 >> 17) * OUTC + c], h2);
        atomicAdd(&acc[(p3 >> 17) * OUTC + c], h3);
    }
    if (wave == 0 && half == 0) {
        for (int i = full; i < cntE; ++i) {
            unsigned p = packed[base + i];
            float h = bf2f(H2s[(size_t)(p & 0x1FFFFu) * OUTC + c]);
            atomicAdd(&acc[(p >> 17) * OUTC + c], h);
        }
    }
    __syncthreads();

    const int node0 = bk << SHIFT;
    for (int k = 0; k < NPB * OUTC / 512; ++k) {
        int idx = t + k * 512;
        int node = node0 + (idx >> 5), ch = idx & 31;
        if (node < N) {
            float o = acc[idx] + bf2f(H2s[(size_t)node * OUTC + ch]);  // self loop
            out[(size_t)node * OUTC + ch] = o * dinv[node] + bias[ch];
        }
    }
}

extern "C" void kernel_launch(void* const* d_in, const int* in_sizes, int n_in,
                              void* d_out, int out_size, void* d_ws, size_t ws_size,
                              hipStream_t stream) {
    const float* x   = (const float*)d_in[0];
    const int*   ei  = (const int*)d_in[1];
    const float* W1  = (const float*)d_in[2];
    const float* b1  = (const float*)d_in[3];
    const float* W2  = (const float*)d_in[4];
    const float* b2  = (const float*)d_in[5];
    float*       out = (float*)d_out;

    const int* srcp = ei;
    const int* dstp = ei + E;

    char* ws = (char*)d_ws;
    int*            gcnt   = (int*)(ws + 0);                   // 3128 B
    int*            bbase  = (int*)(ws + 4096);                // 3128 B
    int*            cursor = (int*)(ws + 12288);               // 3128 B
    float*          dinv   = (float*)(ws + 16384);             // 400 KB
    unsigned*       packed = (unsigned*)(ws + (512u << 10));   // 6.43 MB (padded)
    unsigned short* Hs     = (unsigned short*)(ws + (8u << 20));   // 12.8 MB
    float*          O1     = (float*)(ws + (21u << 20));       // 25.6 MB -> ends 46.6 MB
    unsigned short* H2s    = Hs;                               // reuse: Hs dead after agg1

    hipMemsetAsync(gcnt, 0, NB * sizeof(int), stream);
    k_hist <<<256, 256, 0, stream>>>(dstp, gcnt);
    k_bscan<<<1, 1024, 0, stream>>>(gcnt, bbase, cursor);
    k_part <<<PB, 256, 0, stream>>>(srcp, dstp, cursor, packed);
    k_dinvb<<<NB, 256, 0, stream>>>(bbase, gcnt, packed, dinv);

    k_gemm1<<<N / 32, 256, 0, stream>>>(x, W1, dinv, Hs);
    k_agg1 <<<NB, 512, 0, stream>>>(bbase, gcnt, packed, dinv, Hs, b1, O1);
    k_gemm2<<<N / 32, 256, 0, stream>>>(O1, W2, dinv, H2s);
    k_agg2 <<<NB, 512, 0, stream>>>(bbase, gcnt, packed, dinv, H2s, b2, out);
}

// Round 8
// 281.478 us; speedup vs baseline: 4.3500x; 4.3500x over previous
//
#include <hip/hip_runtime.h>

constexpr int N  = 100000;
constexpr int E  = 1600000;
constexpr int IN = 128, HID = 64, OUTC = 32;

// coarse radix partition params (R6-proven)
constexpr int SHIFT = 9;                       // 512 nodes per bucket
constexpr int NPB   = 1 << SHIFT;              // 512
constexpr int NB    = (N + NPB - 1) / NPB;     // 196 buckets
constexpr int CAP   = 16384;                   // LDS stage cap (mean 8163, sigma~90)
constexpr int PB    = 256;                     // partition blocks
constexpr int CHUNK = E / PB;                  // 6250 (exact)

// ---- bf16 helpers (manual, RNE) ----
__device__ __forceinline__ unsigned short f2bf(float f) {
    union { float f; unsigned int u; } v; v.f = f;
    unsigned int u = v.u;
    unsigned int r = (u + 0x7fffu + ((u >> 16) & 1u)) >> 16;
    return (unsigned short)r;
}
__device__ __forceinline__ float bf2f(unsigned short h) {
    union { unsigned int u; float f; } v; v.u = ((unsigned int)h) << 16;
    return v.f;
}

// ---------------- coarse histogram ----------------
__global__ __launch_bounds__(256) void k_hist(const int* __restrict__ dst,
                                              int* __restrict__ gcnt) {
    __shared__ int h[NB];
    for (int i = threadIdx.x; i < NB; i += 256) h[i] = 0;
    __syncthreads();
    const int tid = blockIdx.x * 256 + threadIdx.x, nt = gridDim.x * 256;
    for (int e = tid; e < E; e += nt) atomicAdd(&h[dst[e] >> SHIFT], 1);
    __syncthreads();
    for (int i = threadIdx.x; i < NB; i += 256)
        if (h[i]) atomicAdd(&gcnt[i], h[i]);
}

// ---------------- scan 196 bucket totals ----------------
__global__ void k_bscan(const int* __restrict__ gcnt, int* __restrict__ base,
                        int* __restrict__ cursor) {
    __shared__ int sb[256];
    const int t = threadIdx.x;
    int v = (t < NB) ? gcnt[t] : 0;
    sb[t] = v; __syncthreads();
    for (int off = 1; off < 256; off <<= 1) {
        int x = (t >= off) ? sb[t - off] : 0;
        __syncthreads();
        sb[t] += x;
        __syncthreads();
    }
    if (t < NB) { int ex = sb[t] - v; base[t] = ex; cursor[t] = ex; }
    if (t == 0) base[NB] = E;
}

// ---------------- partition edges into coarse buckets ----------------
__global__ __launch_bounds__(256) void k_part(const int* __restrict__ src,
                                              const int* __restrict__ dst,
                                              int* __restrict__ cursor,
                                              unsigned* __restrict__ packed) {
    __shared__ int lh[NB], lb[NB], lc[NB];
    const int t = threadIdx.x;
    const int beg = blockIdx.x * CHUNK, end = beg + CHUNK;
    for (int i = t; i < NB; i += 256) lh[i] = 0;
    __syncthreads();
    for (int e = beg + t; e < end; e += 256) atomicAdd(&lh[dst[e] >> SHIFT], 1);
    __syncthreads();
    for (int i = t; i < NB; i += 256) {
        lb[i] = lh[i] ? atomicAdd(&cursor[i], lh[i]) : 0;
        lc[i] = 0;
    }
    __syncthreads();
    for (int e = beg + t; e < end; e += 256) {
        int d = dst[e], b = d >> SHIFT;
        int idx = atomicAdd(&lc[b], 1);
        packed[lb[b] + idx] = ((unsigned)(d & (NPB - 1)) << 17) | (unsigned)src[e];
    }
}

// ---------------- per-bucket CSR build: offs + dinv + in-place sorted csr ----------------
__global__ __launch_bounds__(512) void k_build(const int* __restrict__ bbase,
                                               unsigned* __restrict__ packed,
                                               int* __restrict__ offs,
                                               float* __restrict__ dinv) {
    __shared__ int cnt[NPB];
    __shared__ unsigned stage[CAP];            // 64 KB
    const int t = threadIdx.x, b = blockIdx.x;
    const int base = bbase[b], cntE = bbase[b + 1] - base;
    const int node0 = b << SHIFT;
    cnt[t] = 0;
    __syncthreads();
    for (int i = t; i < cntE; i += 512) atomicAdd(&cnt[packed[base + i] >> 17], 1);
    __syncthreads();
    const int v = cnt[t];
    __syncthreads();
    for (int off = 1; off < NPB; off <<= 1) {
        int x = (t >= off) ? cnt[t - off] : 0;
        __syncthreads();
        cnt[t] += x;
        __syncthreads();
    }
    const int ex = cnt[t] - v;
    const int node = node0 + t;
    if (node < N) {
        offs[node] = base + ex;
        dinv[node] = rsqrtf((float)v + 1.0f);  // +1 self loop
    }
    if (node == N) offs[N] = E;
    __syncthreads();
    cnt[t] = ex;
    __syncthreads();
    for (int i = t; i < cntE; i += 512) {
        unsigned p = packed[base + i];
        int idx = atomicAdd(&cnt[p >> 17], 1);
        if (idx < CAP) stage[idx] = p & 0x1FFFFu;
    }
    __syncthreads();
    for (int i = t; i < cntE; i += 512)
        packed[base + i] = stage[i];           // in-place: csr == packed buffer
}

// ---------------- GEMM1: Hs = bf16(dinv[row] * (X @ W1)) ----------------
__global__ __launch_bounds__(256) void k_gemm1(const float* __restrict__ X,
                                               const float* __restrict__ W,
                                               const float* __restrict__ dinv,
                                               unsigned short* __restrict__ Hs) {
    constexpr int R  = 32;
    constexpr int XS = IN + 4;
    __shared__ float ws[IN * HID];             // 32 KB
    __shared__ float xs[R * XS];
    const int t    = threadIdx.x;
    const int row0 = blockIdx.x * R;

    for (int i = t; i < IN * HID / 4; i += 256)
        ((float4*)ws)[i] = ((const float4*)W)[i];
    for (int i = t; i < R * IN / 4; i += 256) {
        int r = i / (IN / 4), k4 = i % (IN / 4);
        *(float4*)&xs[r * XS + k4 * 4] =
            ((const float4*)(X + (size_t)(row0 + r) * IN))[k4];
    }
    __syncthreads();

    const int col0 = (t & 15) * 4;
    const int r0   = (t >> 4) * 2;
    float4 a0 = {0, 0, 0, 0}, a1 = {0, 0, 0, 0};
    for (int k = 0; k < IN; ++k) {
        float4 w = *(const float4*)&ws[k * HID + col0];
        float x0 = xs[r0 * XS + k];
        float x1 = xs[(r0 + 1) * XS + k];
        a0.x += x0 * w.x; a0.y += x0 * w.y; a0.z += x0 * w.z; a0.w += x0 * w.w;
        a1.x += x1 * w.x; a1.y += x1 * w.y; a1.z += x1 * w.z; a1.w += x1 * w.w;
    }
    const float d0 = dinv[row0 + r0];
    const float d1 = dinv[row0 + r0 + 1];
    ushort4 p0 = {f2bf(a0.x * d0), f2bf(a0.y * d0), f2bf(a0.z * d0), f2bf(a0.w * d0)};
    ushort4 p1 = {f2bf(a1.x * d1), f2bf(a1.y * d1), f2bf(a1.z * d1), f2bf(a1.w * d1)};
    *(ushort4*)(Hs + (size_t)(row0 + r0) * HID + col0)       = p0;
    *(ushort4*)(Hs + (size_t)(row0 + r0 + 1) * HID + col0)   = p1;
}

// ---------------- gather1: O1 = relu(dinv[d]*(Hs[d] + Σ Hs[s]) + b1) ----------------
// Lane-parallel index staging: ONE coalesced csr load per 64 edges into LDS,
// inner loop reads indices via ~6cyc LDS broadcast (no global load in the
// dependency chain) and keeps 8 independent row gathers in flight.
__global__ __launch_bounds__(256) void k_gather1(const int* __restrict__ offs,
                                                 const int* __restrict__ csr,
                                                 const float* __restrict__ dinv,
                                                 const unsigned short* __restrict__ Hs,
                                                 const float* __restrict__ b,
                                                 float* __restrict__ O1) {
    __shared__ int sidx[4][64];
    const int w    = threadIdx.x >> 6;
    const int c    = threadIdx.x & 63;
    const int node = blockIdx.x * 4 + w;                    // N % 4 == 0
    const int beg  = offs[node], end = offs[node + 1];
    float acc0 = bf2f(Hs[(size_t)node * HID + c]);          // self loop (pre-scaled)
    float acc1 = 0.f, acc2 = 0.f, acc3 = 0.f;
    for (int base = beg; base < end; base += 64) {
        const int n = min(64, end - base);
        if (c < n) sidx[w][c] = csr[base + c];              // one coalesced load
        int k = 0;
        for (; k + 7 < n; k += 8) {
            int s0 = sidx[w][k],     s1 = sidx[w][k + 1];
            int s2 = sidx[w][k + 2], s3 = sidx[w][k + 3];
            int s4 = sidx[w][k + 4], s5 = sidx[w][k + 5];
            int s6 = sidx[w][k + 6], s7 = sidx[w][k + 7];
            float h0 = bf2f(Hs[(size_t)s0 * HID + c]);
            float h1 = bf2f(Hs[(size_t)s1 * HID + c]);
            float h2 = bf2f(Hs[(size_t)s2 * HID + c]);
            float h3 = bf2f(Hs[(size_t)s3 * HID + c]);
            float h4 = bf2f(Hs[(size_t)s4 * HID + c]);
            float h5 = bf2f(Hs[(size_t)s5 * HID + c]);
            float h6 = bf2f(Hs[(size_t)s6 * HID + c]);
            float h7 = bf2f(Hs[(size_t)s7 * HID + c]);
            acc0 += h0 + h4;
            acc1 += h1 + h5;
            acc2 += h2 + h6;
            acc3 += h3 + h7;
        }
        for (; k < n; ++k)
            acc0 += bf2f(Hs[(size_t)sidx[w][k] * HID + c]);
    }
    const float dn = dinv[node];
    float o = (acc0 + acc1) + (acc2 + acc3);
    O1[(size_t)node * HID + c] = fmaxf(o * dn + b[c], 0.0f);   // fused relu
}

// ---------------- GEMM2: H2s = bf16(dinv[row] * (O1 @ W2)), O1 pre-relu'd ----------------
__global__ __launch_bounds__(256) void k_gemm2(const float* __restrict__ O1,
                                               const float* __restrict__ W,
                                               const float* __restrict__ dinv,
                                               unsigned short* __restrict__ H2s) {
    constexpr int R  = 32;
    constexpr int XS = HID + 4;
    __shared__ float ws[HID * OUTC];
    __shared__ float xs[R * XS];
    const int t    = threadIdx.x;
    const int row0 = blockIdx.x * R;

    for (int i = t; i < HID * OUTC / 4; i += 256)
        ((float4*)ws)[i] = ((const float4*)W)[i];
    for (int i = t; i < R * HID / 4; i += 256) {
        int r = i / (HID / 4), k4 = i % (HID / 4);
        *(float4*)&xs[r * XS + k4 * 4] =
            ((const float4*)(O1 + (size_t)(row0 + r) * HID))[k4];
    }
    __syncthreads();

    const int col0 = (t & 7) * 4;
    const int r    = t >> 3;
    float4 a = {0, 0, 0, 0};
    for (int k = 0; k < HID; ++k) {
        float4 w = *(const float4*)&ws[k * OUTC + col0];
        float x  = xs[r * XS + k];
        a.x += x * w.x; a.y += x * w.y; a.z += x * w.z; a.w += x * w.w;
    }
    const float dd = dinv[row0 + r];
    ushort4 p = {f2bf(a.x * dd), f2bf(a.y * dd), f2bf(a.z * dd), f2bf(a.w * dd)};
    *(ushort4*)(H2s + (size_t)(row0 + r) * OUTC + col0) = p;
}

// ---------------- gather2: out = dinv[d]*(H2s[d] + Σ H2s[s]) + b2 ----------------
// Same staging; half-wave (32 lanes) per row, 4 rows in flight per half.
__global__ __launch_bounds__(256) void k_gather2(const int* __restrict__ offs,
                                                 const int* __restrict__ csr,
                                                 const float* __restrict__ dinv,
                                                 const unsigned short* __restrict__ H2s,
                                                 const float* __restrict__ b,
                                                 float* __restrict__ out) {
    __shared__ int sidx[4][64];
    const int w    = threadIdx.x >> 6;
    const int lane = threadIdx.x & 63;
    const int c    = lane & 31;
    const int half = lane >> 5;
    const int node = blockIdx.x * 4 + w;
    const int beg  = offs[node], end = offs[node + 1];
    float acc0 = (half == 0) ? bf2f(H2s[(size_t)node * OUTC + c]) : 0.0f;
    float acc1 = 0.f;
    for (int base = beg; base < end; base += 64) {
        const int n = min(64, end - base);
        if (lane < n) sidx[w][lane] = csr[base + lane];
        int k = half;
        for (; k + 6 < n; k += 8) {
            int s0 = sidx[w][k],     s1 = sidx[w][k + 2];
            int s2 = sidx[w][k + 4], s3 = sidx[w][k + 6];
            float h0 = bf2f(H2s[(size_t)s0 * OUTC + c]);
            float h1 = bf2f(H2s[(size_t)s1 * OUTC + c]);
            float h2 = bf2f(H2s[(size_t)s2 * OUTC + c]);
            float h3 = bf2f(H2s[(size_t)s3 * OUTC + c]);
            acc0 += h0 + h2;
            acc1 += h1 + h3;
        }
        for (; k < n; k += 2)
            acc0 += bf2f(H2s[(size_t)sidx[w][k] * OUTC + c]);
    }
    float acc = acc0 + acc1;
    acc += __shfl_down(acc, 32, 64);
    if (half == 0)
        out[(size_t)node * OUTC + c] = acc * dinv[node] + b[c];
}

extern "C" void kernel_launch(void* const* d_in, const int* in_sizes, int n_in,
                              void* d_out, int out_size, void* d_ws, size_t ws_size,
                              hipStream_t stream) {
    const float* x   = (const float*)d_in[0];
    const int*   ei  = (const int*)d_in[1];
    const float* W1  = (const float*)d_in[2];
    const float* b1  = (const float*)d_in[3];
    const float* W2  = (const float*)d_in[4];
    const float* b2  = (const float*)d_in[5];
    float*       out = (float*)d_out;

    const int* srcp = ei;
    const int* dstp = ei + E;

    char* ws = (char*)d_ws;
    int*            gcnt   = (int*)(ws + 0);                   // 784 B
    int*            bbase  = (int*)(ws + 4096);                // 788 B
    int*            cursor = (int*)(ws + 8192);                // 784 B
    int*            offs   = (int*)(ws + 16384);               // 400,004 B
    float*          dinv   = (float*)(ws + (512u << 10));      // 400 KB
    unsigned*       packed = (unsigned*)(ws + (1u << 20));     // 6.4 MB (becomes csr in place)
    unsigned short* Hs     = (unsigned short*)(ws + (8u << 20));   // 12.8 MB
    float*          O1     = (float*)(ws + (21u << 20));       // 25.6 MB -> ends 46.6 MB
    unsigned short* H2s    = Hs;                               // reuse: Hs dead after gather1
    int*            csr    = (int*)packed;

    hipMemsetAsync(gcnt, 0, NB * sizeof(int), stream);
    k_hist <<<256, 256, 0, stream>>>(dstp, gcnt);
    k_bscan<<<1, 256, 0, stream>>>(gcnt, bbase, cursor);
    k_part <<<PB, 256, 0, stream>>>(srcp, dstp, cursor, packed);
    k_build<<<NB, 512, 0, stream>>>(bbase, packed, offs, dinv);

    k_gemm1<<<N / 32, 256, 0, stream>>>(x, W1, dinv, Hs);
    k_gather1<<<N / 4, 256, 0, stream>>>(offs, csr, dinv, Hs, b1, O1);
    k_gemm2<<<N / 32, 256, 0, stream>>>(O1, W2, dinv, H2s);
    k_gather2<<<N / 4, 256, 0, stream>>>(offs, csr, dinv, H2s, b2, out);
}

// Round 9
// 271.343 us; speedup vs baseline: 4.5125x; 1.0374x over previous
//
#include <hip/hip_runtime.h>

constexpr int N  = 100000;
constexpr int E  = 1600000;
constexpr int IN = 128, HID = 64, OUTC = 32;

// coarse radix partition params (R6-proven)
constexpr int SHIFT = 9;                       // 512 nodes per bucket
constexpr int NPB   = 1 << SHIFT;              // 512
constexpr int NB    = (N + NPB - 1) / NPB;     // 196 buckets
constexpr int CAP   = 16384;                   // LDS stage cap (mean 8163, sigma~90)
constexpr int PB    = 256;                     // partition blocks
constexpr int CHUNK = E / PB;                  // 6250 (exact)

// ---- bf16 helpers ----
__device__ __forceinline__ unsigned short f2bf(float f) {
    union { float f; unsigned int u; } v; v.f = f;
    unsigned int u = v.u;
    unsigned int r = (u + 0x7fffu + ((u >> 16) & 1u)) >> 16;
    return (unsigned short)r;
}
__device__ __forceinline__ float bf2f(unsigned short h) {
    union { unsigned int u; float f; } v; v.u = ((unsigned int)h) << 16;
    return v.f;
}
// bf16 pair unpack from dword (low = even ch, high = odd ch)
__device__ __forceinline__ float blo(unsigned u) { return __uint_as_float(u << 16); }
__device__ __forceinline__ float bhi(unsigned u) { return __uint_as_float(u & 0xffff0000u); }

// ---------------- coarse histogram ----------------
__global__ __launch_bounds__(256) void k_hist(const int* __restrict__ dst,
                                              int* __restrict__ gcnt) {
    __shared__ int h[NB];
    for (int i = threadIdx.x; i < NB; i += 256) h[i] = 0;
    __syncthreads();
    const int tid = blockIdx.x * 256 + threadIdx.x, nt = gridDim.x * 256;
    for (int e = tid; e < E; e += nt) atomicAdd(&h[dst[e] >> SHIFT], 1);
    __syncthreads();
    for (int i = threadIdx.x; i < NB; i += 256)
        if (h[i]) atomicAdd(&gcnt[i], h[i]);
}

// ---------------- scan 196 bucket totals ----------------
__global__ void k_bscan(const int* __restrict__ gcnt, int* __restrict__ base,
                        int* __restrict__ cursor) {
    __shared__ int sb[256];
    const int t = threadIdx.x;
    int v = (t < NB) ? gcnt[t] : 0;
    sb[t] = v; __syncthreads();
    for (int off = 1; off < 256; off <<= 1) {
        int x = (t >= off) ? sb[t - off] : 0;
        __syncthreads();
        sb[t] += x;
        __syncthreads();
    }
    if (t < NB) { int ex = sb[t] - v; base[t] = ex; cursor[t] = ex; }
    if (t == 0) base[NB] = E;
}

// ---------------- partition edges into coarse buckets ----------------
__global__ __launch_bounds__(256) void k_part(const int* __restrict__ src,
                                              const int* __restrict__ dst,
                                              int* __restrict__ cursor,
                                              unsigned* __restrict__ packed) {
    __shared__ int lh[NB], lb[NB], lc[NB];
    const int t = threadIdx.x;
    const int beg = blockIdx.x * CHUNK, end = beg + CHUNK;
    for (int i = t; i < NB; i += 256) lh[i] = 0;
    __syncthreads();
    for (int e = beg + t; e < end; e += 256) atomicAdd(&lh[dst[e] >> SHIFT], 1);
    __syncthreads();
    for (int i = t; i < NB; i += 256) {
        lb[i] = lh[i] ? atomicAdd(&cursor[i], lh[i]) : 0;
        lc[i] = 0;
    }
    __syncthreads();
    for (int e = beg + t; e < end; e += 256) {
        int d = dst[e], b = d >> SHIFT;
        int idx = atomicAdd(&lc[b], 1);
        packed[lb[b] + idx] = ((unsigned)(d & (NPB - 1)) << 17) | (unsigned)src[e];
    }
}

// ---------------- per-bucket CSR build: offs + dinv + in-place sorted csr ----------------
__global__ __launch_bounds__(512) void k_build(const int* __restrict__ bbase,
                                               unsigned* __restrict__ packed,
                                               int* __restrict__ offs,
                                               float* __restrict__ dinv) {
    __shared__ int cnt[NPB];
    __shared__ unsigned stage[CAP];            // 64 KB
    const int t = threadIdx.x, b = blockIdx.x;
    const int base = bbase[b], cntE = bbase[b + 1] - base;
    const int node0 = b << SHIFT;
    cnt[t] = 0;
    __syncthreads();
    for (int i = t; i < cntE; i += 512) atomicAdd(&cnt[packed[base + i] >> 17], 1);
    __syncthreads();
    const int v = cnt[t];
    __syncthreads();
    for (int off = 1; off < NPB; off <<= 1) {
        int x = (t >= off) ? cnt[t - off] : 0;
        __syncthreads();
        cnt[t] += x;
        __syncthreads();
    }
    const int ex = cnt[t] - v;
    const int node = node0 + t;
    if (node < N) {
        offs[node] = base + ex;
        dinv[node] = rsqrtf((float)v + 1.0f);  // +1 self loop
    }
    if (node == N) offs[N] = E;
    __syncthreads();
    cnt[t] = ex;
    __syncthreads();
    for (int i = t; i < cntE; i += 512) {
        unsigned p = packed[base + i];
        int idx = atomicAdd(&cnt[p >> 17], 1);
        if (idx < CAP) stage[idx] = p & 0x1FFFFu;
    }
    __syncthreads();
    for (int i = t; i < cntE; i += 512)
        packed[base + i] = stage[i];           // in-place: csr == packed buffer
}

// ---------------- GEMM1: Hs = bf16(dinv[row] * (X @ W1)) ----------------
__global__ __launch_bounds__(256) void k_gemm1(const float* __restrict__ X,
                                               const float* __restrict__ W,
                                               const float* __restrict__ dinv,
                                               unsigned short* __restrict__ Hs) {
    constexpr int R  = 32;
    constexpr int XS = IN + 4;
    __shared__ float ws[IN * HID];             // 32 KB
    __shared__ float xs[R * XS];
    const int t    = threadIdx.x;
    const int row0 = blockIdx.x * R;

    for (int i = t; i < IN * HID / 4; i += 256)
        ((float4*)ws)[i] = ((const float4*)W)[i];
    for (int i = t; i < R * IN / 4; i += 256) {
        int r = i / (IN / 4), k4 = i % (IN / 4);
        *(float4*)&xs[r * XS + k4 * 4] =
            ((const float4*)(X + (size_t)(row0 + r) * IN))[k4];
    }
    __syncthreads();

    const int col0 = (t & 15) * 4;
    const int r0   = (t >> 4) * 2;
    float4 a0 = {0, 0, 0, 0}, a1 = {0, 0, 0, 0};
    for (int k = 0; k < IN; ++k) {
        float4 w = *(const float4*)&ws[k * HID + col0];
        float x0 = xs[r0 * XS + k];
        float x1 = xs[(r0 + 1) * XS + k];
        a0.x += x0 * w.x; a0.y += x0 * w.y; a0.z += x0 * w.z; a0.w += x0 * w.w;
        a1.x += x1 * w.x; a1.y += x1 * w.y; a1.z += x1 * w.z; a1.w += x1 * w.w;
    }
    const float d0 = dinv[row0 + r0];
    const float d1 = dinv[row0 + r0 + 1];
    ushort4 p0 = {f2bf(a0.x * d0), f2bf(a0.y * d0), f2bf(a0.z * d0), f2bf(a0.w * d0)};
    ushort4 p1 = {f2bf(a1.x * d1), f2bf(a1.y * d1), f2bf(a1.z * d1), f2bf(a1.w * d1)};
    *(ushort4*)(Hs + (size_t)(row0 + r0) * HID + col0)       = p0;
    *(ushort4*)(Hs + (size_t)(row0 + r0 + 1) * HID + col0)   = p1;
}

// ---------------- gather1: half-wave per edge, dword (2ch) per lane ----------------
// One VMEM instr fetches TWO edges' rows (halves carry different addresses).
// Index staging in LDS keeps global loads off the dependency chain.
// O1 stored as bf16 pairs (halves write traffic + gemm2 read traffic).
__global__ __launch_bounds__(256) void k_gather1(const int* __restrict__ offs,
                                                 const int* __restrict__ csr,
                                                 const float* __restrict__ dinv,
                                                 const unsigned short* __restrict__ Hs,
                                                 const float* __restrict__ b,
                                                 unsigned* __restrict__ O1h) {
    __shared__ int sidx[4][64];
    const int w    = threadIdx.x >> 6;
    const int lane = threadIdx.x & 63;
    const int c2   = lane & 31;                 // channel pair (2c2, 2c2+1)
    const int half = lane >> 5;
    const int node = blockIdx.x * 4 + w;        // N % 4 == 0
    const int beg  = offs[node], end = offs[node + 1];
    const unsigned* __restrict__ Hu = (const unsigned*)Hs;   // row stride 32 dwords
    float ax0 = 0, ay0 = 0, ax1 = 0, ay1 = 0, ax2 = 0, ay2 = 0, ax3 = 0, ay3 = 0;
    if (half == 0) {                            // self loop (pre-scaled)
        unsigned u = Hu[(size_t)node * 32 + c2];
        ax0 = blo(u); ay0 = bhi(u);
    }
    for (int base = beg; base < end; base += 64) {
        const int n = min(64, end - base);
        if (lane < n) sidx[w][lane] = csr[base + lane];   // one coalesced load
        int k = 0;
        for (; k + 7 < n; k += 8) {             // 8 edges: 4 VMEM instrs in flight
            int s0 = sidx[w][k + half];
            int s1 = sidx[w][k + 2 + half];
            int s2 = sidx[w][k + 4 + half];
            int s3 = sidx[w][k + 6 + half];
            unsigned u0 = Hu[(size_t)s0 * 32 + c2];
            unsigned u1 = Hu[(size_t)s1 * 32 + c2];
            unsigned u2 = Hu[(size_t)s2 * 32 + c2];
            unsigned u3 = Hu[(size_t)s3 * 32 + c2];
            ax0 += blo(u0); ay0 += bhi(u0);
            ax1 += blo(u1); ay1 += bhi(u1);
            ax2 += blo(u2); ay2 += bhi(u2);
            ax3 += blo(u3); ay3 += bhi(u3);
        }
        for (; k + 1 < n; k += 2) {
            int s = sidx[w][k + half];
            unsigned u = Hu[(size_t)s * 32 + c2];
            ax0 += blo(u); ay0 += bhi(u);
        }
        if (k < n && half == 0) {               // odd remainder
            int s = sidx[w][k];
            unsigned u = Hu[(size_t)s * 32 + c2];
            ax1 += blo(u); ay1 += bhi(u);
        }
    }
    float sx = (ax0 + ax1) + (ax2 + ax3);
    float sy = (ay0 + ay1) + (ay2 + ay3);
    sx += __shfl_down(sx, 32, 64);
    sy += __shfl_down(sy, 32, 64);
    if (half == 0) {
        const float dn = dinv[node];
        float2 bb = *(const float2*)(b + 2 * c2);
        float rx = fmaxf(sx * dn + bb.x, 0.0f);           // fused relu
        float ry = fmaxf(sy * dn + bb.y, 0.0f);
        O1h[(size_t)node * 32 + c2] =
            (unsigned)f2bf(rx) | ((unsigned)f2bf(ry) << 16);
    }
}

// ---------------- GEMM2: H2s = bf16(dinv[row] * (bf16(O1) @ W2)) ----------------
__global__ __launch_bounds__(256) void k_gemm2(const unsigned short* __restrict__ O1h,
                                               const float* __restrict__ W,
                                               const float* __restrict__ dinv,
                                               unsigned short* __restrict__ H2s) {
    constexpr int R  = 32;
    constexpr int XS = HID + 4;
    __shared__ float ws[HID * OUTC];
    __shared__ float xs[R * XS];
    const int t    = threadIdx.x;
    const int row0 = blockIdx.x * R;

    for (int i = t; i < HID * OUTC / 4; i += 256)
        ((float4*)ws)[i] = ((const float4*)W)[i];
    for (int i = t; i < R * HID / 4; i += 256) {
        int r = i / (HID / 4), k4 = i % (HID / 4);
        ushort4 v = ((const ushort4*)(O1h + (size_t)(row0 + r) * HID))[k4];
        xs[r * XS + k4 * 4 + 0] = bf2f(v.x);
        xs[r * XS + k4 * 4 + 1] = bf2f(v.y);
        xs[r * XS + k4 * 4 + 2] = bf2f(v.z);
        xs[r * XS + k4 * 4 + 3] = bf2f(v.w);
    }
    __syncthreads();

    const int col0 = (t & 7) * 4;
    const int r    = t >> 3;
    float4 a = {0, 0, 0, 0};
    for (int k = 0; k < HID; ++k) {
        float4 w = *(const float4*)&ws[k * OUTC + col0];
        float x  = xs[r * XS + k];
        a.x += x * w.x; a.y += x * w.y; a.z += x * w.z; a.w += x * w.w;
    }
    const float dd = dinv[row0 + r];
    ushort4 p = {f2bf(a.x * dd), f2bf(a.y * dd), f2bf(a.z * dd), f2bf(a.w * dd)};
    *(ushort4*)(H2s + (size_t)(row0 + r) * OUTC + col0) = p;
}

// ---------------- gather2: quarter-wave per edge, dword (2ch) per lane ----------------
// One VMEM instr fetches FOUR edges' 64B rows.
__global__ __launch_bounds__(256) void k_gather2(const int* __restrict__ offs,
                                                 const int* __restrict__ csr,
                                                 const float* __restrict__ dinv,
                                                 const unsigned short* __restrict__ H2s,
                                                 const float* __restrict__ b,
                                                 float* __restrict__ out) {
    __shared__ int sidx[4][64];
    const int w    = threadIdx.x >> 6;
    const int lane = threadIdx.x & 63;
    const int c2   = lane & 15;                 // channel pair among 16
    const int q    = lane >> 4;                 // quarter 0..3
    const int node = blockIdx.x * 4 + w;
    const int beg  = offs[node], end = offs[node + 1];
    const unsigned* __restrict__ Hu = (const unsigned*)H2s;  // row stride 16 dwords
    float ax0 = 0, ay0 = 0, ax1 = 0, ay1 = 0;
    if (q == 0) {                               // self loop
        unsigned u = Hu[(size_t)node * 16 + c2];
        ax0 = blo(u); ay0 = bhi(u);
    }
    for (int base = beg; base < end; base += 64) {
        const int n = min(64, end - base);
        if (lane < n) sidx[w][lane] = csr[base + lane];
        int k = 0;
        for (; k + 7 < n; k += 8) {             // 8 edges: 2 VMEM instrs
            int s0 = sidx[w][k + q];
            int s1 = sidx[w][k + 4 + q];
            unsigned u0 = Hu[(size_t)s0 * 16 + c2];
            unsigned u1 = Hu[(size_t)s1 * 16 + c2];
            ax0 += blo(u0); ay0 += bhi(u0);
            ax1 += blo(u1); ay1 += bhi(u1);
        }
        for (; k < n; k += 4) {
            if (k + q < n) {
                int s = sidx[w][k + q];
                unsigned u = Hu[(size_t)s * 16 + c2];
                ax1 += blo(u); ay1 += bhi(u);
            }
        }
    }
    float sx = ax0 + ax1, sy = ay0 + ay1;
    sx += __shfl_down(sx, 32, 64); sy += __shfl_down(sy, 32, 64);
    sx += __shfl_down(sx, 16, 64); sy += __shfl_down(sy, 16, 64);
    if (q == 0) {
        const float dn = dinv[node];
        float2 bb = *(const float2*)(b + 2 * c2);
        float2 r;
        r.x = sx * dn + bb.x;
        r.y = sy * dn + bb.y;
        *(float2*)(out + (size_t)node * OUTC + 2 * c2) = r;
    }
}

extern "C" void kernel_launch(void* const* d_in, const int* in_sizes, int n_in,
                              void* d_out, int out_size, void* d_ws, size_t ws_size,
                              hipStream_t stream) {
    const float* x   = (const float*)d_in[0];
    const int*   ei  = (const int*)d_in[1];
    const float* W1  = (const float*)d_in[2];
    const float* b1  = (const float*)d_in[3];
    const float* W2  = (const float*)d_in[4];
    const float* b2  = (const float*)d_in[5];
    float*       out = (float*)d_out;

    const int* srcp = ei;
    const int* dstp = ei + E;

    char* ws = (char*)d_ws;
    int*            gcnt   = (int*)(ws + 0);                   // 784 B
    int*            bbase  = (int*)(ws + 4096);                // 788 B
    int*            cursor = (int*)(ws + 8192);                // 784 B
    int*            offs   = (int*)(ws + 16384);               // 400,004 B
    float*          dinv   = (float*)(ws + (512u << 10));      // 400 KB
    unsigned*       packed = (unsigned*)(ws + (1u << 20));     // 6.4 MB (becomes csr in place)
    unsigned short* Hs     = (unsigned short*)(ws + (8u << 20));   // 12.8 MB
    unsigned*       O1h    = (unsigned*)(ws + (21u << 20));    // 12.8 MB (bf16) -> ends 33.8 MB
    unsigned short* H2s    = Hs;                               // reuse: Hs dead after gather1
    int*            csr    = (int*)packed;

    hipMemsetAsync(gcnt, 0, NB * sizeof(int), stream);
    k_hist <<<256, 256, 0, stream>>>(dstp, gcnt);
    k_bscan<<<1, 256, 0, stream>>>(gcnt, bbase, cursor);
    k_part <<<PB, 256, 0, stream>>>(srcp, dstp, cursor, packed);
    k_build<<<NB, 512, 0, stream>>>(bbase, packed, offs, dinv);

    k_gemm1<<<N / 32, 256, 0, stream>>>(x, W1, dinv, Hs);
    k_gather1<<<N / 4, 256, 0, stream>>>(offs, csr, dinv, Hs, b1, O1h);
    k_gemm2<<<N / 32, 256, 0, stream>>>((const unsigned short*)O1h, W2, dinv, H2s);
    k_gather2<<<N / 4, 256, 0, stream>>>(offs, csr, dinv, H2s, b2, out);
}